// Round 8
// baseline (857.865 us; speedup 1.0000x reference)
//
#include <hip/hip_runtime.h>
#include <hip/hip_bf16.h>

typedef __bf16 bf16_t;
typedef __bf16 bf16x4_t __attribute__((ext_vector_type(4)));
typedef __bf16 bf16x8  __attribute__((ext_vector_type(8)));
typedef float  f32x4   __attribute__((ext_vector_type(4)));

#define T_LEN 200
#define D_DIM 256

__device__ __forceinline__ float fast_tanh(float x) {
    float e = __expf(2.0f * x);
    return 1.0f - 2.0f / (e + 1.0f);
}

// DCE-protection sinks (guide rule #17)
__device__ __forceinline__ void sink_f(float v) { asm volatile("" :: "v"(v)); }
__device__ __forceinline__ void sink_f4(f32x4 v) {
    asm volatile("" :: "v"(v[0]), "v"(v[1]), "v"(v[2]), "v"(v[3]));
}
__device__ __forceinline__ void sink_bf8(bf16x8 v) {
    f32x4 f = __builtin_bit_cast(f32x4, v);
    sink_f4(f);
}

// ---------------------------------------------------------------------------
// Kernel 1a: qpart[b][d] = sum_k Q[b][k] * W1[d][k]  (f32) -> d_out (scratch)
// ---------------------------------------------------------------------------
__global__ __launch_bounds__(256) void qpart_kernel(
    const float* __restrict__ Q, const float* __restrict__ W1,
    float* __restrict__ Out)
{
    __shared__ float qs[8][256];
    const int tid = threadIdx.x;
    const int b0  = blockIdx.x * 8;
    for (int idx = tid; idx < 8 * 256; idx += 256)
        qs[idx >> 8][idx & 255] = Q[(size_t)(b0 + (idx >> 8)) * 256 + (idx & 255)];
    __syncthreads();
    float acc[8];
    #pragma unroll
    for (int i = 0; i < 8; ++i) acc[i] = 0.f;
    const f32x4* Wv = (const f32x4*)(W1 + (size_t)tid * 512);
    #pragma unroll 4
    for (int k4 = 0; k4 < 64; ++k4) {
        f32x4 w = Wv[k4];
        #pragma unroll
        for (int bb = 0; bb < 8; ++bb) {
            f32x4 qv = *(const f32x4*)&qs[bb][k4 * 4];
            acc[bb] += qv[0]*w[0] + qv[1]*w[1] + qv[2]*w[2] + qv[3]*w[3];
        }
    }
    #pragma unroll
    for (int bb = 0; bb < 8; ++bb)
        Out[(size_t)(b0 + bb) * 256 + tid] = acc[bb];
}

// ---------------------------------------------------------------------------
// Kernel 1b: W1b (= W1[:,256:512]) -> bf16, row-major [256][256] in ws.
// ---------------------------------------------------------------------------
__global__ __launch_bounds__(256) void convw_kernel(
    const float* __restrict__ W1, bf16_t* __restrict__ bfW)
{
    const int d = blockIdx.x;
    const int k = threadIdx.x;
    bfW[(size_t)d * 256 + k] = (bf16_t)W1[(size_t)d * 512 + 256 + k];
}

// ---------------------------------------------------------------------------
// Kernel 2 (ablation): v5 structure, template<MODE> phase stubs.
//   MODE 1: stage + fragment loads only (sinks keep them live)
//   MODE 2: + MFMA clusters (accs sunk; no tanh/shfl/atomic)
//   MODE 3: + tail + exp/denominator (no PV)
//   MODE 0: full — the real computation (writes WsNum/WsL)
// rocprof per-dispatch dur_us gives the phase cost breakdown.
// ---------------------------------------------------------------------------
template<bool SPLIT, int MODE>
__global__ __launch_bounds__(512, 4) void attn_abl_kernel(
    const float* __restrict__ U,      // [B,200,256]
    const int*   __restrict__ Mask,   // [B,200]
    const float* __restrict__ W1,     // [256,512] (fallback frag source)
    const float* __restrict__ W2,     // [256]
    const bf16_t* __restrict__ bfW,   // [256][256] bf16 W1b (SPLIT only)
    float* Out,                       // qpart on entry; !SPLIT: final out
    float* __restrict__ WsNum,        // [grid][256] (SPLIT, MODE 0)
    float* __restrict__ WsL,          // [grid]      (SPLIT, MODE 0)
    float* __restrict__ WsAbl)        // [grid] ablation sink (MODE 1..3)
{
    constexpr int MAXROW = SPLIT ? 64 : 224;
    __shared__ bf16_t tiles[MAXROW * 256];   // XOR-swizzled
    __shared__ float score_lds[MAXROW];
    __shared__ float p_lds[MAXROW];
    __shared__ float out_lds[4][256];
    __shared__ float l_red;

    const int tid  = threadIdx.x;
    const int lane = tid & 63;
    const int wv   = tid >> 6;   // wave 0..7 -> d block [wv*32, wv*32+32)
    const int lr   = lane & 15;
    const int lg   = lane >> 4;

    int b, t0, nrow, nreal;
    if (SPLIT) {
        b = blockIdx.x >> 2;
        const int h = blockIdx.x & 3;
        t0    = h * 56;
        nreal = (h == 3) ? 32 : 56;
        nrow  = (h == 3) ? 32 : 64;
    } else {
        b = blockIdx.x; t0 = 0; nreal = 200; nrow = 224;
    }
    char* const tbase = (char*)tiles;

    if (tid < nrow) score_lds[tid] = 0.f;
    if (tid == 0)   l_red = 0.f;

    // ---- A-fragments: W1b rows d = wv*32 + sub*16 + lr ----
    bf16x8 aw[2][8];
    #pragma unroll
    for (int sub = 0; sub < 2; ++sub) {
        const int d = wv * 32 + sub * 16 + lr;
        if (SPLIT) {
            #pragma unroll
            for (int kk = 0; kk < 8; ++kk)
                aw[sub][kk] = *(const bf16x8*)(bfW + (size_t)d * 256 + kk * 32 + lg * 8);
        } else {
            const float* wrow = W1 + (size_t)d * 512 + 256;
            #pragma unroll
            for (int kk = 0; kk < 8; ++kk) {
                const float* s = wrow + kk * 32 + lg * 8;
                f32x4 lo = *(const f32x4*)s;
                f32x4 hi = *(const f32x4*)(s + 4);
                bf16x8 v;
                v[0]=(bf16_t)lo[0]; v[1]=(bf16_t)lo[1]; v[2]=(bf16_t)lo[2]; v[3]=(bf16_t)lo[3];
                v[4]=(bf16_t)hi[0]; v[5]=(bf16_t)hi[1]; v[6]=(bf16_t)hi[2]; v[7]=(bf16_t)hi[3];
                aw[sub][kk] = v;
            }
        }
    }
    // per-lane d for C rows: d = wv*32 + sub*16 + lg*4 + r
    float w2v[2][4], qpv[2][4];
    #pragma unroll
    for (int sub = 0; sub < 2; ++sub)
        #pragma unroll
        for (int r = 0; r < 4; ++r) {
            const int d = wv * 32 + sub * 16 + lg * 4 + r;
            w2v[sub][r] = W2[d];
            qpv[sub][r] = Out[(size_t)b * 256 + d];
        }

    // ---- stage rows (wave-owned) ----
    {
        const float* Ub = U + (size_t)b * (T_LEN * D_DIM);
        const int ni = nrow >> 3;
        for (int i = 0; i < ni; ++i) {
            const int r = wv + i * 8;
            bf16x4_t v;
            v[0]=(bf16_t)0.f; v[1]=(bf16_t)0.f; v[2]=(bf16_t)0.f; v[3]=(bf16_t)0.f;
            if (r < nreal) {
                f32x4 g = *(const f32x4*)(Ub + (size_t)(t0 + r) * 256 + lane * 4);
                v[0]=(bf16_t)g[0]; v[1]=(bf16_t)g[1]; v[2]=(bf16_t)g[2]; v[3]=(bf16_t)g[3];
            }
            *(bf16x4_t*)(tbase + r * 512 + ((lane * 8) ^ ((r & 7) << 4))) = v;
        }
    }
    __syncthreads();

    if (MODE == 1) {
        // sink fragments + scalars + one LDS readback; then stop.
        #pragma unroll
        for (int sub = 0; sub < 2; ++sub)
            #pragma unroll
            for (int kk = 0; kk < 8; ++kk) sink_bf8(aw[sub][kk]);
        #pragma unroll
        for (int sub = 0; sub < 2; ++sub)
            #pragma unroll
            for (int r = 0; r < 4; ++r) { sink_f(w2v[sub][r]); sink_f(qpv[sub][r]); }
        const unsigned off = ((unsigned)tid * 8u) & (unsigned)(MAXROW * 512 - 8);
        float2 dv = *(const float2*)(tbase + off);
        sink_f(dv.x); sink_f(dv.y);
        if (tid == 0) WsAbl[blockIdx.x] = dv.x;
        return;
    }

    // ---- compute: 2 t-tiles per MFMA cluster ----
    const int npair = nrow >> 5;
    for (int pp = 0; pp < npair; ++pp) {
        f32x4 a00 = {0,0,0,0}, a01 = {0,0,0,0};
        f32x4 a10 = {0,0,0,0}, a11 = {0,0,0,0};
        const int r0 = pp * 32 + lr;
        const int r1 = r0 + 16;
        __builtin_amdgcn_s_setprio(1);
        #pragma unroll
        for (int kk = 0; kk < 8; ++kk) {
            const unsigned kb = (unsigned)(kk * 64 + lg * 16);
            bf16x8 u0 = *(const bf16x8*)(tbase + r0 * 512 + (kb ^ (((unsigned)r0 & 7) << 4)));
            bf16x8 u1 = *(const bf16x8*)(tbase + r1 * 512 + (kb ^ (((unsigned)r1 & 7) << 4)));
            a00 = __builtin_amdgcn_mfma_f32_16x16x32_bf16(aw[0][kk], u0, a00, 0, 0, 0);
            a01 = __builtin_amdgcn_mfma_f32_16x16x32_bf16(aw[1][kk], u0, a01, 0, 0, 0);
            a10 = __builtin_amdgcn_mfma_f32_16x16x32_bf16(aw[0][kk], u1, a10, 0, 0, 0);
            a11 = __builtin_amdgcn_mfma_f32_16x16x32_bf16(aw[1][kk], u1, a11, 0, 0, 0);
        }
        __builtin_amdgcn_s_setprio(0);

        if (MODE == 2) {
            sink_f4(a00); sink_f4(a01); sink_f4(a10); sink_f4(a11);
            continue;
        }

        // tails: in-lane weighted tanh sum over 8 d's, 2 shfl, 1 atomic
        float s0 = 0.f, s1 = 0.f;
        #pragma unroll
        for (int r = 0; r < 4; ++r) {
            s0 += w2v[0][r] * fast_tanh(a00[r] + qpv[0][r]);
            s0 += w2v[1][r] * fast_tanh(a01[r] + qpv[1][r]);
            s1 += w2v[0][r] * fast_tanh(a10[r] + qpv[0][r]);
            s1 += w2v[1][r] * fast_tanh(a11[r] + qpv[1][r]);
        }
        s0 += __shfl_xor(s0, 16); s0 += __shfl_xor(s0, 32);
        s1 += __shfl_xor(s1, 16); s1 += __shfl_xor(s1, 32);
        if (lg == 0) {
            atomicAdd(&score_lds[pp * 32 + lr], s0);
            atomicAdd(&score_lds[pp * 32 + 16 + lr], s1);
        }
    }

    if (MODE == 2) {
        if (tid == 0) WsAbl[blockIdx.x] = 1.0f;
        return;
    }
    __syncthreads();   // scores complete

    // ---- p = exp(masked s) (no-max), denominator ----
    {
        float p = 0.f;
        if (tid < nreal)
            p = Mask[(size_t)b * T_LEN + t0 + tid] ? 1.0f : __expf(score_lds[tid]);
        if (tid < nrow) p_lds[tid] = p;   // pad rows stay 0
        float ps = p;
        ps += __shfl_xor(ps, 1);
        ps += __shfl_xor(ps, 2);
        ps += __shfl_xor(ps, 4);
        ps += __shfl_xor(ps, 8);
        ps += __shfl_xor(ps, 16);
        ps += __shfl_xor(ps, 32);
        if (lane == 0 && ps != 0.f) atomicAdd(&l_red, ps);
    }
    __syncthreads();   // p, l ready

    if (MODE == 3) {
        const float pv = (tid < nrow) ? p_lds[tid] : 0.f;
        sink_f(pv); sink_f(l_red);
        if (tid == 0) WsAbl[blockIdx.x] = l_red;
        return;
    }

    // ---- PV from LDS bf16 ----
    {
        const int dp = tid & 127;   // bf16 pair {2dp, 2dp+1}
        const int jg = tid >> 7;
        const int qr = nrow >> 2;
        float o0 = 0.f, o1 = 0.f;
        for (int i = 0; i < qr; ++i) {
            const int j = jg * qr + i;
            const float p = p_lds[j];
            const unsigned w = *(const unsigned*)(tbase + j * 512
                             + (((unsigned)(dp * 4)) ^ (((unsigned)j & 7) << 4)));
            o0 += p * __builtin_bit_cast(float, w << 16);
            o1 += p * __builtin_bit_cast(float, w & 0xffff0000u);
        }
        *(float2*)&out_lds[jg][dp * 2] = make_float2(o0, o1);
    }
    __syncthreads();

    if (tid < 256) {
        const float num = out_lds[0][tid] + out_lds[1][tid]
                        + out_lds[2][tid] + out_lds[3][tid];
        if (SPLIT) WsNum[(size_t)blockIdx.x * 256 + tid] = num;
        else       Out[(size_t)b * 256 + tid] = num / l_red;
    }
    if (SPLIT && tid == 0) WsL[blockIdx.x] = l_red;
}

// ---------------------------------------------------------------------------
// Kernel 3: out[b][d] = sum_h num[h] / sum_h l[h]   (4 quarters)
// ---------------------------------------------------------------------------
__global__ __launch_bounds__(256) void combine_kernel(
    const float* __restrict__ WsNum, const float* __restrict__ WsL,
    float* __restrict__ Out)
{
    const int b = blockIdx.x, tid = threadIdx.x;
    float n = 0.f;
    #pragma unroll
    for (int h = 0; h < 4; ++h)
        n += WsNum[(size_t)(4 * b + h) * 256 + tid];
    const float l = WsL[4*b] + WsL[4*b+1] + WsL[4*b+2] + WsL[4*b+3];
    Out[(size_t)b * 256 + tid] = n / l;
}

extern "C" void kernel_launch(void* const* d_in, const int* in_sizes, int n_in,
                              void* d_out, int out_size, void* d_ws, size_t ws_size,
                              hipStream_t stream)
{
    const float* Q  = (const float*)d_in[0];
    const float* U  = (const float*)d_in[1];
    const int*   Mk = (const int*)d_in[2];
    const float* W1 = (const float*)d_in[3];
    const float* W2 = (const float*)d_in[4];
    float* Out = (float*)d_out;
    const int B = in_sizes[0] / D_DIM;   // 2048

    qpart_kernel<<<dim3(B / 8), dim3(256), 0, stream>>>(Q, W1, Out);

    const size_t nblk = (size_t)B * 4;
    const size_t need = nblk * 256 * 4 + nblk * 4 + 256 * 256 * 2 + nblk * 4;
    if (ws_size >= need) {
        float*  wsn = (float*)d_ws;
        float*  wsl = wsn + nblk * 256;
        bf16_t* bfw = (bf16_t*)(wsl + nblk);
        float*  wsa = (float*)(bfw + 256 * 256);
        convw_kernel<<<dim3(256), dim3(256), 0, stream>>>(W1, bfw);
        // --- ablation dispatches (diagnostic; results sunk to wsa) ---
        attn_abl_kernel<true, 1><<<dim3((unsigned)nblk), dim3(512), 0, stream>>>(
            U, Mk, W1, W2, bfw, Out, wsn, wsl, wsa);
        attn_abl_kernel<true, 2><<<dim3((unsigned)nblk), dim3(512), 0, stream>>>(
            U, Mk, W1, W2, bfw, Out, wsn, wsl, wsa);
        attn_abl_kernel<true, 3><<<dim3((unsigned)nblk), dim3(512), 0, stream>>>(
            U, Mk, W1, W2, bfw, Out, wsn, wsl, wsa);
        // --- the real computation ---
        attn_abl_kernel<true, 0><<<dim3((unsigned)nblk), dim3(512), 0, stream>>>(
            U, Mk, W1, W2, bfw, Out, wsn, wsl, wsa);
        combine_kernel<<<dim3(B), dim3(256), 0, stream>>>(wsn, wsl, Out);
    } else {
        attn_abl_kernel<false, 0><<<dim3(B), dim3(512), 0, stream>>>(
            U, Mk, W1, W2, nullptr, Out, nullptr, nullptr, nullptr);
    }
}

// Round 9
// 290.173 us; speedup vs baseline: 2.9564x; 2.9564x over previous
//
#include <hip/hip_runtime.h>
#include <hip/hip_bf16.h>

typedef __bf16 bf16_t;
typedef __bf16 bf16x4_t __attribute__((ext_vector_type(4)));
typedef __bf16 bf16x8  __attribute__((ext_vector_type(8)));
typedef float  f32x4   __attribute__((ext_vector_type(4)));

#define T_LEN 200
#define D_DIM 256

__device__ __forceinline__ float fast_tanh(float x) {
    float e = __expf(2.0f * x);
    return 1.0f - 2.0f / (e + 1.0f);
}

// async global->LDS DMA, 16 B/lane; LDS dest = wave-uniform base + lane*16
__device__ __forceinline__ void gload_lds16(const float* g, char* l) {
    __builtin_amdgcn_global_load_lds(
        (const __attribute__((address_space(1))) unsigned int*)g,
        (__attribute__((address_space(3))) unsigned int*)l,
        16, 0, 0);
}

// ---------------------------------------------------------------------------
// Kernel 1a: qpart[b][d] = sum_k Q[b][k] * W1[d][k]  (f32) -> d_out (scratch)
// ---------------------------------------------------------------------------
__global__ __launch_bounds__(256) void qpart_kernel(
    const float* __restrict__ Q, const float* __restrict__ W1,
    float* __restrict__ Out)
{
    __shared__ float qs[8][256];
    const int tid = threadIdx.x;
    const int b0  = blockIdx.x * 8;
    for (int idx = tid; idx < 8 * 256; idx += 256)
        qs[idx >> 8][idx & 255] = Q[(size_t)(b0 + (idx >> 8)) * 256 + (idx & 255)];
    __syncthreads();
    float acc[8];
    #pragma unroll
    for (int i = 0; i < 8; ++i) acc[i] = 0.f;
    const f32x4* Wv = (const f32x4*)(W1 + (size_t)tid * 512);
    #pragma unroll 4
    for (int k4 = 0; k4 < 64; ++k4) {
        f32x4 w = Wv[k4];
        #pragma unroll
        for (int bb = 0; bb < 8; ++bb) {
            f32x4 qv = *(const f32x4*)&qs[bb][k4 * 4];
            acc[bb] += qv[0]*w[0] + qv[1]*w[1] + qv[2]*w[2] + qv[3]*w[3];
        }
    }
    #pragma unroll
    for (int bb = 0; bb < 8; ++bb)
        Out[(size_t)(b0 + bb) * 256 + tid] = acc[bb];
}

// ---------------------------------------------------------------------------
// Kernel 1b: W1b (= W1[:,256:512]) -> bf16, row-major [256][256] in ws.
// ---------------------------------------------------------------------------
__global__ __launch_bounds__(256) void convw_kernel(
    const float* __restrict__ W1, bf16_t* __restrict__ bfW)
{
    const int d = blockIdx.x;
    const int k = threadIdx.x;
    bfW[(size_t)d * 256 + k] = (bf16_t)W1[(size_t)d * 512 + 256 + k];
}

// ---------------------------------------------------------------------------
// Kernel 2 (v8): quarter-batch blocks; f32 LDS tile staged via
// global_load_lds (burst DMA, no reg round-trip, no per-iteration dependency
// chain -> Little's-law fix for the 0.85 TB/s staging wall). Bank-conflict
// freedom via pre-swizzled GLOBAL source (16B-chunk c = lane ^ (r&7)), with
// the matching XOR on every LDS read. bf16 cvt happens at fragment build.
// Swapped MFMA operands (A=W1b regs, B=ub^T) keep the W2-dot in-lane.
// No-max softmax (|s| <= ||W2||_1 ~ 13). Partials -> ws; combine divides.
// ---------------------------------------------------------------------------
template<bool SPLIT>
__global__ __launch_bounds__(512, SPLIT ? 4 : 2) void attn_v8_kernel(
    const float* __restrict__ U,      // [B,200,256]
    const int*   __restrict__ Mask,   // [B,200]
    const float* __restrict__ W1,     // [256,512] (fallback frag source)
    const float* __restrict__ W2,     // [256]
    const bf16_t* __restrict__ bfW,   // [256][256] bf16 W1b (SPLIT only)
    float* Out,                       // qpart on entry; !SPLIT: final out
    float* __restrict__ WsNum,        // [grid][256] (SPLIT)
    float* __restrict__ WsL)          // [grid]      (SPLIT)
{
    constexpr int MAXROW = SPLIT ? 64 : 224;
    constexpr int ROWB   = SPLIT ? 1024 : 512;   // f32 rows vs bf16 rows
    __shared__ char tbase[MAXROW * ROWB];
    __shared__ float score_lds[MAXROW];
    __shared__ float p_lds[MAXROW];
    __shared__ float out_lds[4][256];
    __shared__ float l_red;

    const int tid  = threadIdx.x;
    const int lane = tid & 63;
    const int wv   = tid >> 6;   // wave 0..7 -> d block [wv*32, wv*32+32)
    const int lr   = lane & 15;
    const int lg   = lane >> 4;

    int b, t0, nrow, nreal;
    if (SPLIT) {
        b = blockIdx.x >> 2;
        const int h = blockIdx.x & 3;
        t0    = h * 56;
        nreal = (h == 3) ? 32 : 56;
        nrow  = (h == 3) ? 32 : 64;
    } else {
        b = blockIdx.x; t0 = 0; nreal = 200; nrow = 224;
    }

    if (tid < nrow) score_lds[tid] = 0.f;
    if (tid == 0)   l_red = 0.f;

    const float* Ub = U + (size_t)b * (T_LEN * D_DIM);

    // ---- stage rows: burst-issued, all DMAs in flight at once ----
    if constexpr (SPLIT) {
        const int nwrow = nrow >> 3;    // 8 or 4 rows per wave
        #pragma unroll
        for (int i = 0; i < 8; ++i) {
            if (i < nwrow) {
                const int r  = wv + i * 8;                 // wave-uniform
                const int rr = (r < nreal) ? r : (nreal - 1);  // clamp pads
                const unsigned c = (unsigned)lane ^ ((unsigned)r & 7u);
                gload_lds16(Ub + (size_t)(t0 + rr) * 256 + c * 4,
                            tbase + (size_t)r * 1024);
            }
        }
    } else {
        const int ni = nrow >> 3;
        for (int i = 0; i < ni; ++i) {
            const int r = wv + i * 8;
            bf16x4_t v; v[0]=(bf16_t)0.f; v[1]=(bf16_t)0.f;
            v[2]=(bf16_t)0.f; v[3]=(bf16_t)0.f;
            if (r < nreal) {
                f32x4 g = *(const f32x4*)(Ub + (size_t)(t0 + r) * 256 + lane * 4);
                v[0]=(bf16_t)g[0]; v[1]=(bf16_t)g[1]; v[2]=(bf16_t)g[2]; v[3]=(bf16_t)g[3];
            }
            *(bf16x4_t*)(tbase + r * 512 + ((lane * 8) ^ ((r & 7) << 4))) = v;
        }
    }

    // ---- A-fragments: W1b rows d = wv*32 + sub*16 + lr (64 VGPR) ----
    bf16x8 aw[2][8];
    #pragma unroll
    for (int sub = 0; sub < 2; ++sub) {
        const int d = wv * 32 + sub * 16 + lr;
        if (SPLIT) {
            #pragma unroll
            for (int kk = 0; kk < 8; ++kk)
                aw[sub][kk] = *(const bf16x8*)(bfW + (size_t)d * 256 + kk * 32 + lg * 8);
        } else {
            const float* wrow = W1 + (size_t)d * 512 + 256;
            #pragma unroll
            for (int kk = 0; kk < 8; ++kk) {
                const float* s = wrow + kk * 32 + lg * 8;
                f32x4 lo = *(const f32x4*)s;
                f32x4 hi = *(const f32x4*)(s + 4);
                bf16x8 v;
                v[0]=(bf16_t)lo[0]; v[1]=(bf16_t)lo[1]; v[2]=(bf16_t)lo[2]; v[3]=(bf16_t)lo[3];
                v[4]=(bf16_t)hi[0]; v[5]=(bf16_t)hi[1]; v[6]=(bf16_t)hi[2]; v[7]=(bf16_t)hi[3];
                aw[sub][kk] = v;
            }
        }
    }
    // per-lane d for C rows: d = wv*32 + sub*16 + lg*4 + r
    float w2v[2][4], qpv[2][4];
    #pragma unroll
    for (int sub = 0; sub < 2; ++sub)
        #pragma unroll
        for (int r = 0; r < 4; ++r) {
            const int d = wv * 32 + sub * 16 + lg * 4 + r;
            w2v[sub][r] = W2[d];
            qpv[sub][r] = Out[(size_t)b * 256 + d];
        }

    asm volatile("s_waitcnt vmcnt(0)" ::: "memory");   // DMA + frag loads done
    __syncthreads();

    // ---- compute: 2 t-tiles per MFMA cluster, qpart as acc init ----
    const int npair = nrow >> 5;
    for (int pp = 0; pp < npair; ++pp) {
        f32x4 a00 = {qpv[0][0], qpv[0][1], qpv[0][2], qpv[0][3]};
        f32x4 a01 = {qpv[1][0], qpv[1][1], qpv[1][2], qpv[1][3]};
        f32x4 a10 = a00, a11 = a01;
        const int r0 = pp * 32 + lr;
        const int r1 = r0 + 16;
        if constexpr (SPLIT) {
            const unsigned b0 = (unsigned)r0 << 10, b1 = (unsigned)r1 << 10;
            const unsigned s0 = ((unsigned)r0 & 7u) << 4;
            const unsigned s1 = ((unsigned)r1 & 7u) << 4;
            #pragma unroll
            for (int kk = 0; kk < 8; ++kk) {
                const unsigned K = (unsigned)(kk * 128 + lg * 32);
                f32x4 x0 = *(const f32x4*)(tbase + b0 + (K ^ s0));
                f32x4 x1 = *(const f32x4*)(tbase + b0 + ((K + 16) ^ s0));
                f32x4 y0 = *(const f32x4*)(tbase + b1 + (K ^ s1));
                f32x4 y1 = *(const f32x4*)(tbase + b1 + ((K + 16) ^ s1));
                bf16x8 u0, u1;
                u0[0]=(bf16_t)x0[0]; u0[1]=(bf16_t)x0[1]; u0[2]=(bf16_t)x0[2]; u0[3]=(bf16_t)x0[3];
                u0[4]=(bf16_t)x1[0]; u0[5]=(bf16_t)x1[1]; u0[6]=(bf16_t)x1[2]; u0[7]=(bf16_t)x1[3];
                u1[0]=(bf16_t)y0[0]; u1[1]=(bf16_t)y0[1]; u1[2]=(bf16_t)y0[2]; u1[3]=(bf16_t)y0[3];
                u1[4]=(bf16_t)y1[0]; u1[5]=(bf16_t)y1[1]; u1[6]=(bf16_t)y1[2]; u1[7]=(bf16_t)y1[3];
                a00 = __builtin_amdgcn_mfma_f32_16x16x32_bf16(aw[0][kk], u0, a00, 0, 0, 0);
                a01 = __builtin_amdgcn_mfma_f32_16x16x32_bf16(aw[1][kk], u0, a01, 0, 0, 0);
                a10 = __builtin_amdgcn_mfma_f32_16x16x32_bf16(aw[0][kk], u1, a10, 0, 0, 0);
                a11 = __builtin_amdgcn_mfma_f32_16x16x32_bf16(aw[1][kk], u1, a11, 0, 0, 0);
            }
        } else {
            #pragma unroll
            for (int kk = 0; kk < 8; ++kk) {
                const unsigned kb = (unsigned)(kk * 64 + lg * 16);
                bf16x8 u0 = *(const bf16x8*)(tbase + r0 * 512 + (kb ^ (((unsigned)r0 & 7) << 4)));
                bf16x8 u1 = *(const bf16x8*)(tbase + r1 * 512 + (kb ^ (((unsigned)r1 & 7) << 4)));
                a00 = __builtin_amdgcn_mfma_f32_16x16x32_bf16(aw[0][kk], u0, a00, 0, 0, 0);
                a01 = __builtin_amdgcn_mfma_f32_16x16x32_bf16(aw[1][kk], u0, a01, 0, 0, 0);
                a10 = __builtin_amdgcn_mfma_f32_16x16x32_bf16(aw[0][kk], u1, a10, 0, 0, 0);
                a11 = __builtin_amdgcn_mfma_f32_16x16x32_bf16(aw[1][kk], u1, a11, 0, 0, 0);
            }
        }

        // tails: in-lane weighted tanh sum over 8 d's, 2 shfl, 1 atomic
        float s0 = 0.f, s1 = 0.f;
        #pragma unroll
        for (int r = 0; r < 4; ++r) {
            s0 += w2v[0][r] * fast_tanh(a00[r]);
            s0 += w2v[1][r] * fast_tanh(a01[r]);
            s1 += w2v[0][r] * fast_tanh(a10[r]);
            s1 += w2v[1][r] * fast_tanh(a11[r]);
        }
        s0 += __shfl_xor(s0, 16); s0 += __shfl_xor(s0, 32);
        s1 += __shfl_xor(s1, 16); s1 += __shfl_xor(s1, 32);
        if (lg == 0) {
            atomicAdd(&score_lds[pp * 32 + lr], s0);
            atomicAdd(&score_lds[pp * 32 + 16 + lr], s1);
        }
    }
    __syncthreads();   // scores complete

    // ---- p = exp(masked s) (no-max), denominator ----
    {
        float p = 0.f;
        if (tid < nreal)
            p = Mask[(size_t)b * T_LEN + t0 + tid] ? 1.0f : __expf(score_lds[tid]);
        if (tid < nrow) p_lds[tid] = p;   // pad rows stay 0
        float ps = p;
        ps += __shfl_xor(ps, 1);
        ps += __shfl_xor(ps, 2);
        ps += __shfl_xor(ps, 4);
        ps += __shfl_xor(ps, 8);
        ps += __shfl_xor(ps, 16);
        ps += __shfl_xor(ps, 32);
        if (lane == 0 && ps != 0.f) atomicAdd(&l_red, ps);
    }
    __syncthreads();   // p, l ready

    // ---- PV from LDS ----
    {
        const int dp = tid & 127;   // col pair {2dp, 2dp+1}
        const int jg = tid >> 7;
        const int qr = nrow >> 2;
        float o0 = 0.f, o1 = 0.f;
        for (int i = 0; i < qr; ++i) {
            const int j = jg * qr + i;
            const float p = p_lds[j];
            if constexpr (SPLIT) {
                const unsigned off = ((unsigned)j << 10)
                                   + (((unsigned)(dp * 8)) ^ (((unsigned)j & 7u) << 4));
                const float2 u = *(const float2*)(tbase + off);
                o0 += p * u.x;
                o1 += p * u.y;
            } else {
                const unsigned w = *(const unsigned*)(tbase + j * 512
                                 + (((unsigned)(dp * 4)) ^ (((unsigned)j & 7) << 4)));
                o0 += p * __builtin_bit_cast(float, w << 16);
                o1 += p * __builtin_bit_cast(float, w & 0xffff0000u);
            }
        }
        *(float2*)&out_lds[jg][dp * 2] = make_float2(o0, o1);
    }
    __syncthreads();

    if (tid < 256) {
        const float num = out_lds[0][tid] + out_lds[1][tid]
                        + out_lds[2][tid] + out_lds[3][tid];
        if (SPLIT) WsNum[(size_t)blockIdx.x * 256 + tid] = num;
        else       Out[(size_t)b * 256 + tid] = num / l_red;
    }
    if (SPLIT && tid == 0) WsL[blockIdx.x] = l_red;
}

// ---------------------------------------------------------------------------
// Kernel 3: out[b][d] = sum_h num[h] / sum_h l[h]   (4 quarters)
// ---------------------------------------------------------------------------
__global__ __launch_bounds__(256) void combine_kernel(
    const float* __restrict__ WsNum, const float* __restrict__ WsL,
    float* __restrict__ Out)
{
    const int b = blockIdx.x, tid = threadIdx.x;
    float n = 0.f;
    #pragma unroll
    for (int h = 0; h < 4; ++h)
        n += WsNum[(size_t)(4 * b + h) * 256 + tid];
    const float l = WsL[4*b] + WsL[4*b+1] + WsL[4*b+2] + WsL[4*b+3];
    Out[(size_t)b * 256 + tid] = n / l;
}

extern "C" void kernel_launch(void* const* d_in, const int* in_sizes, int n_in,
                              void* d_out, int out_size, void* d_ws, size_t ws_size,
                              hipStream_t stream)
{
    const float* Q  = (const float*)d_in[0];
    const float* U  = (const float*)d_in[1];
    const int*   Mk = (const int*)d_in[2];
    const float* W1 = (const float*)d_in[3];
    const float* W2 = (const float*)d_in[4];
    float* Out = (float*)d_out;
    const int B = in_sizes[0] / D_DIM;   // 2048

    qpart_kernel<<<dim3(B / 8), dim3(256), 0, stream>>>(Q, W1, Out);

    const size_t nblk = (size_t)B * 4;
    const size_t need = nblk * 256 * 4 + nblk * 4 + 256 * 256 * 2;
    if (ws_size >= need) {
        float*  wsn = (float*)d_ws;
        float*  wsl = wsn + nblk * 256;
        bf16_t* bfw = (bf16_t*)(wsl + nblk);
        convw_kernel<<<dim3(256), dim3(256), 0, stream>>>(W1, bfw);
        attn_v8_kernel<true><<<dim3((unsigned)nblk), dim3(512), 0, stream>>>(
            U, Mk, W1, W2, bfw, Out, wsn, wsl);
        combine_kernel<<<dim3(B), dim3(256), 0, stream>>>(wsn, wsl, Out);
    } else {
        attn_v8_kernel<false><<<dim3(B), dim3(512), 0, stream>>>(
            U, Mk, W1, W2, nullptr, Out, nullptr, nullptr);
    }
}